// Round 1
// baseline (96.559 us; speedup 1.0000x reference)
//
#include <hip/hip_runtime.h>
#include <math.h>

// FeatureLabelLoss: features (B,C,D) f32, embeddings (C,D) f32, labels (B,C) f32
// -> scalar f32 loss.
// Memory-bound: one streaming read of features (327.7 MB) dominates.

constexpr int B = 32;
constexpr int C = 5000;
constexpr int D = 512;            // 512 floats = 128 float4 per row
constexpr int NROWS = B * C;      // 160000
constexpr int BLOCKS = 2048;
constexpr int THREADS = 256;      // 4 waves per block
constexpr float EPS_NORM = 1e-12f;
constexpr float EPS_LOG = 1e-6f;

__global__ __launch_bounds__(THREADS) void fll_main(
    const float* __restrict__ feat,
    const float* __restrict__ emb,
    const float* __restrict__ labels,
    float* __restrict__ partial)
{
    const int lane = threadIdx.x & 63;
    const int wave = threadIdx.x >> 6;
    __shared__ float wsum[THREADS / 64];

    float wacc = 0.0f;  // accumulated (pos+neg) loss, lane 0 of each wave only

    for (int row = blockIdx.x * 4 + wave; row < NROWS; row += gridDim.x * 4) {
        const int c = row % C;
        const float4* fr = reinterpret_cast<const float4*>(feat + (size_t)row * D);
        const float4* er = reinterpret_cast<const float4*>(emb + (size_t)c * D);

        // 512 floats / 64 lanes = 8 floats (2 float4) per lane, fully coalesced
        float4 f0 = fr[lane];
        float4 f1 = fr[lane + 64];
        float4 e0 = er[lane];
        float4 e1 = er[lane + 64];

        float dot = f0.x * e0.x + f0.y * e0.y + f0.z * e0.z + f0.w * e0.w
                  + f1.x * e1.x + f1.y * e1.y + f1.z * e1.z + f1.w * e1.w;
        float fss = f0.x * f0.x + f0.y * f0.y + f0.z * f0.z + f0.w * f0.w
                  + f1.x * f1.x + f1.y * f1.y + f1.z * f1.z + f1.w * f1.w;
        float ess = e0.x * e0.x + e0.y * e0.y + e0.z * e0.z + e0.w * e0.w
                  + e1.x * e1.x + e1.y * e1.y + e1.z * e1.z + e1.w * e1.w;

        // butterfly reduce across the 64-lane wave
        #pragma unroll
        for (int off = 32; off > 0; off >>= 1) {
            dot += __shfl_xor(dot, off, 64);
            fss += __shfl_xor(fss, off, 64);
            ess += __shfl_xor(ess, off, 64);
        }

        if (lane == 0) {
            float nf = fmaxf(sqrtf(fss), EPS_NORM);
            float ne = fmaxf(sqrtf(ess), EPS_NORM);
            float sim = dot / (nf * ne);
            float lab = labels[row];
            float S = 0.5f * (1.0f + sim) + EPS_LOG;
            float neg_arg = 1.0f
                - ((float)(C - 1) / (float)C) * fabsf(1.0f / (float)(C - 1) + sim)
                + EPS_LOG;
            wacc += lab * logf(S) + (1.0f - lab) * logf(neg_arg);
        }
    }

    if (lane == 0) wsum[wave] = wacc;
    __syncthreads();
    if (threadIdx.x == 0) {
        float s = 0.0f;
        #pragma unroll
        for (int w = 0; w < THREADS / 64; ++w) s += wsum[w];
        partial[blockIdx.x] = s;  // written fresh every launch (deterministic)
    }
}

__global__ __launch_bounds__(THREADS) void fll_reduce(
    const float* __restrict__ partial, float* __restrict__ out)
{
    const int lane = threadIdx.x & 63;
    const int wave = threadIdx.x >> 6;
    double acc = 0.0;
    for (int i = threadIdx.x; i < BLOCKS; i += THREADS) acc += (double)partial[i];

    #pragma unroll
    for (int off = 32; off > 0; off >>= 1) acc += __shfl_xor(acc, off, 64);

    __shared__ double s[THREADS / 64];
    if (lane == 0) s[wave] = acc;
    __syncthreads();
    if (threadIdx.x == 0) {
        double tot = 0.0;
        #pragma unroll
        for (int w = 0; w < THREADS / 64; ++w) tot += s[w];
        out[0] = (float)(-tot / (double)NROWS);
    }
}

extern "C" void kernel_launch(void* const* d_in, const int* in_sizes, int n_in,
                              void* d_out, int out_size, void* d_ws, size_t ws_size,
                              hipStream_t stream) {
    const float* feat   = (const float*)d_in[0];   // (B, C, D)
    const float* emb    = (const float*)d_in[1];   // (C, D)
    const float* labels = (const float*)d_in[2];   // (B, C)
    float* out = (float*)d_out;
    float* partial = (float*)d_ws;                 // BLOCKS floats, rewritten each call

    fll_main<<<BLOCKS, THREADS, 0, stream>>>(feat, emb, labels, partial);
    fll_reduce<<<1, THREADS, 0, stream>>>(partial, out);
}

// Round 2
// 65.185 us; speedup vs baseline: 1.4813x; 1.4813x over previous
//
#include <hip/hip_runtime.h>
#include <math.h>

// FeatureLabelLoss: features (B,C,D) f32, embeddings (C,D) f32, labels (B,C) f32
// -> scalar f32 loss.
// Memory-bound on the single streaming read of features (327.7 MB).
// Restructure: one wave owns a column c; embedding row lives in registers,
// streamed against 16 feature rows (half of B). Halves VMEM instr/row,
// 12 shuffles/row instead of 18, one logf/row instead of two.

constexpr int B = 32;
constexpr int C = 5000;
constexpr int D = 512;                 // 512 floats = 2 float4 per lane
constexpr int NROWS = B * C;           // 160000
constexpr float EPS_NORM = 1e-12f;
constexpr float EPS_LOG = 1e-6f;

constexpr int WAVES_PER_C = 2;         // each wave handles 16 of the 32 b's
constexpr int B_PER_WAVE = B / WAVES_PER_C;        // 16
constexpr int WPB = 4;                              // waves per block
constexpr int MAIN_BLOCKS = C * WAVES_PER_C / WPB;  // 2500
constexpr int THREADS = WPB * 64;                   // 256

__global__ __launch_bounds__(THREADS) void fll_main(
    const float* __restrict__ feat,
    const float* __restrict__ emb,
    const float* __restrict__ labels,
    float* __restrict__ partial)
{
    const int lane = threadIdx.x & 63;
    const int wid  = threadIdx.x >> 6;
    const int gw   = blockIdx.x * WPB + wid;   // 0 .. 9999
    const int c    = gw >> 1;                  // WAVES_PER_C == 2
    const int half = gw & 1;

    // Embedding row for this c: loaded ONCE, kept in registers (8 floats/lane)
    const float4* er = reinterpret_cast<const float4*>(emb + (size_t)c * D);
    const float4 e0 = er[lane];
    const float4 e1 = er[lane + 64];

    float ess = e0.x * e0.x + e0.y * e0.y + e0.z * e0.z + e0.w * e0.w
              + e1.x * e1.x + e1.y * e1.y + e1.z * e1.z + e1.w * e1.w;
    #pragma unroll
    for (int off = 32; off > 0; off >>= 1) ess += __shfl_xor(ess, off, 64);
    const float inv_ne = 1.0f / fmaxf(sqrtf(ess), EPS_NORM);

    const size_t bstride = (size_t)C * D;
    const float* fbase = feat + (size_t)(half * B_PER_WAVE) * bstride + (size_t)c * D;
    const float* lbase = labels + (size_t)(half * B_PER_WAVE) * C + c;

    float wacc = 0.0f;  // identical across all lanes (no divergent tail math)

    #pragma unroll 4
    for (int i = 0; i < B_PER_WAVE; ++i) {
        const float4* fr = reinterpret_cast<const float4*>(fbase + (size_t)i * bstride);
        const float4 f0 = fr[lane];
        const float4 f1 = fr[lane + 64];

        float dot = f0.x * e0.x + f0.y * e0.y + f0.z * e0.z + f0.w * e0.w
                  + f1.x * e1.x + f1.y * e1.y + f1.z * e1.z + f1.w * e1.w;
        float fss = f0.x * f0.x + f0.y * f0.y + f0.z * f0.z + f0.w * f0.w
                  + f1.x * f1.x + f1.y * f1.y + f1.z * f1.z + f1.w * f1.w;

        // two independent butterflies, interleaved for latency overlap
        #pragma unroll
        for (int off = 32; off > 0; off >>= 1) {
            dot += __shfl_xor(dot, off, 64);
            fss += __shfl_xor(fss, off, 64);
        }

        const float inv_nf = 1.0f / fmaxf(sqrtf(fss), EPS_NORM);
        const float sim = dot * inv_nf * inv_ne;
        const float lab = lbase[(size_t)i * C];  // wave-uniform -> s_load
        const float S = 0.5f * (1.0f + sim) + EPS_LOG;
        const float T = 1.0f
            - ((float)(C - 1) / (float)C) * fabsf(1.0f / (float)(C - 1) + sim)
            + EPS_LOG;
        // labels are exactly 0.0 or 1.0: lab*log(S)+(1-lab)*log(T) == log(lab?S:T)
        wacc += logf(lab > 0.5f ? S : T);
    }

    __shared__ float wsum[WPB];
    if (lane == 0) wsum[wid] = wacc;
    __syncthreads();
    if (threadIdx.x == 0) {
        float s = 0.0f;
        #pragma unroll
        for (int w = 0; w < WPB; ++w) s += wsum[w];
        partial[blockIdx.x] = s;  // written fresh every launch
    }
}

__global__ __launch_bounds__(THREADS) void fll_reduce(
    const float* __restrict__ partial, float* __restrict__ out)
{
    const int lane = threadIdx.x & 63;
    const int wave = threadIdx.x >> 6;
    double acc = 0.0;
    for (int i = threadIdx.x; i < MAIN_BLOCKS; i += THREADS) acc += (double)partial[i];

    #pragma unroll
    for (int off = 32; off > 0; off >>= 1) acc += __shfl_xor(acc, off, 64);

    __shared__ double s[THREADS / 64];
    if (lane == 0) s[wave] = acc;
    __syncthreads();
    if (threadIdx.x == 0) {
        double tot = 0.0;
        #pragma unroll
        for (int w = 0; w < THREADS / 64; ++w) tot += s[w];
        out[0] = (float)(-tot / (double)NROWS);
    }
}

extern "C" void kernel_launch(void* const* d_in, const int* in_sizes, int n_in,
                              void* d_out, int out_size, void* d_ws, size_t ws_size,
                              hipStream_t stream) {
    const float* feat   = (const float*)d_in[0];   // (B, C, D)
    const float* emb    = (const float*)d_in[1];   // (C, D)
    const float* labels = (const float*)d_in[2];   // (B, C)
    float* out = (float*)d_out;
    float* partial = (float*)d_ws;                 // MAIN_BLOCKS floats

    fll_main<<<MAIN_BLOCKS, THREADS, 0, stream>>>(feat, emb, labels, partial);
    fll_reduce<<<1, THREADS, 0, stream>>>(partial, out);
}